// Round 6
// baseline (252.699 us; speedup 1.0000x reference)
//
#include <hip/hip_runtime.h>
#include <hip/hip_bf16.h>
#include <hip/hip_cooperative_groups.h>

namespace cg = cooperative_groups;

// Problem constants (from reference)
#define Hd   768
#define Bsz  4
#define Ent  42
#define Mm   16
#define NEGV (-1e9f)

#define GM 2688          // B*E*M rows
#define GN 1536          // concat(head, tail) outputs
#define GK 768
#define NT (GK / 32)     // 24 K-steps

#define GRID 504         // = (GN/128)*(GM/64) gemm tiles; 504 <= 4 blocks/CU cap
#define NTHR 256

typedef short bf16x8 __attribute__((ext_vector_type(8)));
typedef float f32x4  __attribute__((ext_vector_type(4)));
typedef unsigned short u16x8 __attribute__((ext_vector_type(8)));

static __device__ __forceinline__ unsigned short f2bf(float x) {
    unsigned int u = __float_as_uint(x);
    u += 0x7fffu + ((u >> 16) & 1u);          // RNE
    return (unsigned short)(u >> 16);
}
static __device__ __forceinline__ float bf2f(unsigned short v) {
    return __uint_as_float(((unsigned int)v) << 16);
}

// ---------------------------------------------------------------------------
// ONE cooperative kernel, 4 phases separated by grid.sync().
// Phase bodies identical to the round-5 kernels (proven correct/fast);
// the only change is launch fusion to remove ~14us of inter-dispatch overhead.
// ---------------------------------------------------------------------------
__global__ __launch_bounds__(NTHR, 4)
void fused_all(const float* __restrict__ entity_embed,
               const float* __restrict__ mention_embed,
               const int* __restrict__ mention_num,
               const int* __restrict__ b_ind,
               const int* __restrict__ h_ind,
               const int* __restrict__ t_ind,
               const float* __restrict__ W_head,
               const float* __restrict__ W_tail,
               const float* __restrict__ w_c,
               const float* __restrict__ w_q,
               const float* __restrict__ w_cq,
               unsigned short* __restrict__ Ab,      // ws: bf16 staging
               unsigned short* __restrict__ f_head,
               unsigned short* __restrict__ f_tail,
               float* __restrict__ ch, float* __restrict__ qt,
               float* __restrict__ cqt,
               float* __restrict__ out, int N)
{
    cg::grid_group grid = cg::this_grid();

    const int tid  = threadIdx.x;
    const int bid  = blockIdx.x;
    const int wave = tid >> 6;
    const int lane = tid & 63;

    __shared__ unsigned short As[2][64 * 32];    // gemm phase: 4 KB/buf
    __shared__ unsigned short Bs[2][128 * 32];   // gemm phase: 8 KB/buf
    __shared__ float sm[Mm][Mm];                 // pair phase
    __shared__ float hw[Mm], tw[Mm];

    // ====================== phase 0: fp32 -> bf16 ==========================
    // dst rows: [0,2688)=mention_embed, [2688,3456)=W_head, [3456,4224)=W_tail
    {
        const int total = (GM + GN) * GK / 8;    // 405504 threads of 8 elems
        for (int t = bid * NTHR + tid; t < total; t += GRID * NTHR) {
            const size_t e = (size_t)t * 8;
            const size_t row = e / Hd;           // 8 | 768 so no straddle
            const float* src;
            size_t off;
            if (row < 2688)      { src = mention_embed; off = e; }
            else if (row < 3456) { src = W_head; off = e - (size_t)2688 * Hd; }
            else                 { src = W_tail; off = e - (size_t)3456 * Hd; }
            float4 v0 = *reinterpret_cast<const float4*>(src + off);
            float4 v1 = *reinterpret_cast<const float4*>(src + off + 4);
            u16x8 o;
            o[0] = f2bf(v0.x); o[1] = f2bf(v0.y); o[2] = f2bf(v0.z); o[3] = f2bf(v0.w);
            o[4] = f2bf(v1.x); o[5] = f2bf(v1.y); o[6] = f2bf(v1.z); o[7] = f2bf(v1.w);
            *reinterpret_cast<u16x8*>(Ab + e) = o;
        }
    }
    grid.sync();

    // ====================== phase 1: MFMA GEMM + ReLU ======================
    // 64x128 tile (MxN), BK=32, 4 waves, wave = 64 rows x 32-col slice.
    // tile id = bid: bx = bid % 12 (N), by = bid / 12 (M).  504 tiles exactly.
    {
        const unsigned short* Wb = Ab + (size_t)GM * GK;   // weights follow A
        const int n0 = (bid % (GN / 128)) * 128;
        const int m0 = (bid / (GN / 128)) * 64;

        const int srow = wave * 16 + (lane >> 2);          // 0..63
        const int scol = (lane & 3) * 8;                   // elements
        const unsigned short* Aga = Ab + (size_t)(m0 + srow) * GK + scol;
        const unsigned short* Bga = Wb + (size_t)(n0 + srow) * GK + scol;

#define STAGE(buf, k0) do { \
    __builtin_amdgcn_global_load_lds((const __attribute__((address_space(1))) void*)(Aga + (k0)), \
        (__attribute__((address_space(3))) void*)(As[buf] + wave * 512), 16, 0, 0); \
    __builtin_amdgcn_global_load_lds((const __attribute__((address_space(1))) void*)(Bga + (k0)), \
        (__attribute__((address_space(3))) void*)(Bs[buf] + wave * 512), 16, 0, 0); \
    __builtin_amdgcn_global_load_lds((const __attribute__((address_space(1))) void*)(Bga + 64 * GK + (k0)), \
        (__attribute__((address_space(3))) void*)(Bs[buf] + 2048 + wave * 512), 16, 0, 0); \
} while (0)

        const int frow = lane & 15;
        const int koff = (lane >> 4) * 8;

        f32x4 acc[4][2];
        {
            f32x4 z = {0.f, 0.f, 0.f, 0.f};
            #pragma unroll
            for (int mi = 0; mi < 4; ++mi) { acc[mi][0] = z; acc[mi][1] = z; }
        }

        STAGE(0, 0);
        int cur = 0;
        #pragma unroll 1
        for (int t = 0; t < NT; ++t) {
            __syncthreads();             // drains vmcnt: buf[cur] ready
            if (t < NT - 1) STAGE(cur ^ 1, (t + 1) * 32);
            const unsigned short* ap = As[cur] + frow * 32 + koff;
            const unsigned short* bp = Bs[cur] + (wave * 32 + frow) * 32 + koff;
            bf16x8 a[4], b[2];
            #pragma unroll
            for (int mi = 0; mi < 4; ++mi)
                a[mi] = *reinterpret_cast<const bf16x8*>(ap + mi * 16 * 32);
            b[0] = *reinterpret_cast<const bf16x8*>(bp);
            b[1] = *reinterpret_cast<const bf16x8*>(bp + 16 * 32);
            #pragma unroll
            for (int mi = 0; mi < 4; ++mi) {
                acc[mi][0] = __builtin_amdgcn_mfma_f32_16x16x32_bf16(a[mi], b[0], acc[mi][0], 0, 0, 0);
                acc[mi][1] = __builtin_amdgcn_mfma_f32_16x16x32_bf16(a[mi], b[1], acc[mi][1], 0, 0, 0);
            }
            cur ^= 1;
        }
#undef STAGE

        // C/D layout (m89-verified): col = lane&15, row = (lane>>4)*4 + reg.
        const bool isHead = (n0 < Hd);
        unsigned short* outp = isHead ? f_head : f_tail;
        const int nbase = (isHead ? n0 : (n0 - Hd)) + wave * 32 + frow;
        const int rbase = m0 + (lane >> 4) * 4;
        #pragma unroll
        for (int mi = 0; mi < 4; ++mi)
            #pragma unroll
            for (int ni = 0; ni < 2; ++ni)
                #pragma unroll
                for (int j = 0; j < 4; ++j) {
                    float v = fmaxf(acc[mi][ni][j], 0.f);
                    outp[(size_t)(rbase + mi * 16 + j) * Hd + nbase + ni * 16] = f2bf(v);
                }
    }
    grid.sync();

    // ====================== phase 2: per-row dots ==========================
    {
        for (int r = bid * 4 + wave; r < GM; r += GRID * 4) {
            const unsigned short* fh = f_head + (size_t)r * Hd;
            const unsigned short* ft = f_tail + (size_t)r * Hd;
            float pc = 0.f, pq = 0.f, pcq = 0.f;
            #pragma unroll
            for (int j = 0; j < Hd / 64; ++j) {
                const int c = j * 64 + lane;
                float vh = bf2f(fh[c]), vt = bf2f(ft[c]);
                pc += vh * w_c[c]; pq += vt * w_q[c]; pcq += vt * w_cq[c];
            }
            #pragma unroll
            for (int s = 32; s >= 1; s >>= 1) {
                pc  += __shfl_down(pc, s);
                pq  += __shfl_down(pq, s);
                pcq += __shfl_down(pcq, s);
            }
            if (lane == 0) { ch[r] = pc; qt[r] = pq; cqt[r] = pcq; }
        }
    }
    grid.sync();

    // ====================== phase 3: per-pair attention ====================
    for (int n = bid; n < N; n += GRID) {
        const int b = b_ind[n], h = h_ind[n], t = t_ind[n];
        const int eh = b * Ent + h, et = b * Ent + t;
        const int rh = eh * Mm, rt = et * Mm;
        const int hn = mention_num[eh], tn = mention_num[et];

        {
            const int i = tid >> 4, j = tid & 15;
            float v;
            if (i < hn && j < tn)
                v = ch[rh + i] + qt[rt + j]
                  + cqt[rt + i] * bf2f(f_head[(size_t)(rh + i) * Hd + j]);
            else
                v = NEGV;
            sm[i][j] = v;
        }
        __syncthreads();

        if (tid < Mm) {                 // row max (over j) -> hw
            float m = sm[tid][0];
            #pragma unroll
            for (int jj = 1; jj < Mm; ++jj) m = fmaxf(m, sm[tid][jj]);
            hw[tid] = m;
        } else if (tid < 2 * Mm) {      // col max (over i) -> tw
            const int c = tid - Mm;
            float m = sm[0][c];
            #pragma unroll
            for (int ii = 1; ii < Mm; ++ii) m = fmaxf(m, sm[ii][c]);
            tw[c] = m;
        }
        __syncthreads();

        if (tid == 0) {
            float mx = hw[0];
            #pragma unroll
            for (int ii = 1; ii < Mm; ++ii) mx = fmaxf(mx, hw[ii]);
            float e[Mm]; float s = 0.f;
            #pragma unroll
            for (int ii = 0; ii < Mm; ++ii) { e[ii] = expf(hw[ii] - mx); s += e[ii]; }
            const float inv = 1.f / s;
            #pragma unroll
            for (int ii = 0; ii < Mm; ++ii) hw[ii] = e[ii] * inv;
        } else if (tid == 64) {
            float mx = tw[0];
            #pragma unroll
            for (int ii = 1; ii < Mm; ++ii) mx = fmaxf(mx, tw[ii]);
            float e[Mm]; float s = 0.f;
            #pragma unroll
            for (int ii = 0; ii < Mm; ++ii) { e[ii] = expf(tw[ii] - mx); s += e[ii]; }
            const float inv = 1.f / s;
            #pragma unroll
            for (int ii = 0; ii < Mm; ++ii) tw[ii] = e[ii] * inv;
        }
        __syncthreads();

        const size_t oh = (size_t)n * (2 * Hd);
        const size_t ot = (size_t)(N + n) * (2 * Hd);

        if (tid < 192) {
            // weighted pooling: rows >= cnt have weight exactly 0 (softmax
            // underflow of NEG rows) -> bounding the loop is bit-exact.
            const int half = (tid >= 96);
            const int c8 = (tid - half * 96) * 8;
            const int cnt = half ? tn : hn;
            const float* wgt = half ? tw : hw;
            const unsigned short* fp =
                (half ? f_tail + (size_t)rt * Hd : f_head + (size_t)rh * Hd) + c8;
            float a[8] = {0.f, 0.f, 0.f, 0.f, 0.f, 0.f, 0.f, 0.f};
            for (int ii = 0; ii < cnt; ++ii) {
                u16x8 v = *reinterpret_cast<const u16x8*>(fp + (size_t)ii * Hd);
                const float w = wgt[ii];
                #pragma unroll
                for (int j = 0; j < 8; ++j) a[j] += w * bf2f(v[j]);
            }
            float* dst = out + (half ? ot : oh) + Hd + c8;
            float4 o0 = {a[0], a[1], a[2], a[3]};
            float4 o1 = {a[4], a[5], a[6], a[7]};
            *reinterpret_cast<float4*>(dst)     = o0;
            *reinterpret_cast<float4*>(dst + 4) = o1;
        } else {
            // 64 threads copy 2x768 f32 entity embeds = 384 float4, 6 each
            const int q = tid - 192;
            #pragma unroll
            for (int k = q; k < 384; k += 64) {
                const int half = k / 192;
                const int c4 = k - half * 192;
                const float4* src =
                    reinterpret_cast<const float4*>(entity_embed + (size_t)(half ? et : eh) * Hd) + c4;
                float4* dst = reinterpret_cast<float4*>(out + (half ? ot : oh)) + c4;
                *dst = *src;
            }
        }
        __syncthreads();   // sm/hw/tw reads done before next pair overwrites
    }
}

// ---------------------------------------------------------------------------
extern "C" void kernel_launch(void* const* d_in, const int* in_sizes, int n_in,
                              void* d_out, int out_size, void* d_ws, size_t ws_size,
                              hipStream_t stream)
{
    const float* entity_embed  = (const float*)d_in[0];
    const float* mention_embed = (const float*)d_in[1];
    // d_in[2] sent_embed, d_in[3] entity_info: unused by reference
    const int*   mention_num   = (const int*)d_in[4];
    const int*   b_ind         = (const int*)d_in[5];
    const int*   h_ind         = (const int*)d_in[6];
    const int*   t_ind         = (const int*)d_in[7];
    const float* W_head        = (const float*)d_in[8];
    const float* W_tail        = (const float*)d_in[9];
    const float* w_c           = (const float*)d_in[10];
    const float* w_q           = (const float*)d_in[11];
    const float* w_cq          = (const float*)d_in[12];
    float* out = (float*)d_out;

    int N = in_sizes[5];                  // 4096

    // workspace layout (bf16 activations): total ~14.8 MiB
    unsigned short* Ab     = (unsigned short*)d_ws;          // [2688*768] + [1536*768] weights
    unsigned short* f_head = Ab + (size_t)(GM + GN) * GK;    // [2688*768]
    unsigned short* f_tail = f_head + (size_t)GM * Hd;       // [2688*768]
    float* ch  = (float*)(f_tail + (size_t)GM * Hd);
    float* qt  = ch + GM;
    float* cqt = qt + GM;

    void* args[] = {
        (void*)&entity_embed, (void*)&mention_embed, (void*)&mention_num,
        (void*)&b_ind, (void*)&h_ind, (void*)&t_ind,
        (void*)&W_head, (void*)&W_tail, (void*)&w_c, (void*)&w_q, (void*)&w_cq,
        (void*)&Ab, (void*)&f_head, (void*)&f_tail,
        (void*)&ch, (void*)&qt, (void*)&cqt, (void*)&out, (void*)&N
    };
    hipLaunchCooperativeKernel((const void*)fused_all, dim3(GRID), dim3(NTHR),
                               args, 0, stream);
}

// Round 7
// 50.653 us; speedup vs baseline: 4.9888x; 4.9888x over previous
//
#include <hip/hip_runtime.h>
#include <hip/hip_bf16.h>

// Problem constants (from reference)
#define Hd   768
#define Bsz  4
#define Ent  42
#define Mm   16
#define NEGV (-1e9f)

#define GM 2688          // B*E*M rows
#define GN 1536          // concat(head, tail) outputs
#define GK 768
#define NT (GK / 32)     // 24 K-steps

typedef short bf16x8 __attribute__((ext_vector_type(8)));
typedef float f32x4  __attribute__((ext_vector_type(4)));
typedef unsigned short u16x8 __attribute__((ext_vector_type(8)));
typedef unsigned short u16x4 __attribute__((ext_vector_type(4)));

static __device__ __forceinline__ unsigned short f2bf(float x) {
    unsigned int u = __float_as_uint(x);
    u += 0x7fffu + ((u >> 16) & 1u);          // RNE
    return (unsigned short)(u >> 16);
}
static __device__ __forceinline__ float bf2f(unsigned short v) {
    return __uint_as_float(((unsigned int)v) << 16);
}

// ---------------------------------------------------------------------------
// Kernel 0: fp32 -> bf16 conversion (identical to round 5).
// ---------------------------------------------------------------------------
__global__ __launch_bounds__(256)
void to_bf16(const float* __restrict__ me, const float* __restrict__ wh,
             const float* __restrict__ wt, unsigned short* __restrict__ dst)
{
    const int t = blockIdx.x * 256 + threadIdx.x;
    const size_t e = (size_t)t * 8;
    const size_t row = e / Hd;                         // 8 | 768 so no straddle
    const float* src;
    size_t off;
    if (row < 2688)      { src = me; off = e; }
    else if (row < 3456) { src = wh; off = e - (size_t)2688 * Hd; }
    else                 { src = wt; off = e - (size_t)3456 * Hd; }
    float4 v0 = *reinterpret_cast<const float4*>(src + off);
    float4 v1 = *reinterpret_cast<const float4*>(src + off + 4);
    u16x8 o;
    o[0] = f2bf(v0.x); o[1] = f2bf(v0.y); o[2] = f2bf(v0.z); o[3] = f2bf(v0.w);
    o[4] = f2bf(v1.x); o[5] = f2bf(v1.y); o[6] = f2bf(v1.z); o[7] = f2bf(v1.w);
    *reinterpret_cast<u16x8*>(dst + e) = o;
}

// ---------------------------------------------------------------------------
// Kernel 1: bf16 MFMA GEMM + ReLU (identical to round 5).
// 64x128 tile (MxN), BK=32, 4 waves, 2 blocks/CU, dbuf 2-phase prefetch.
// ---------------------------------------------------------------------------
__global__ __launch_bounds__(256)
void gemm_mfma(const unsigned short* __restrict__ Ab,
               const unsigned short* __restrict__ Wb,
               unsigned short* __restrict__ f_head,
               unsigned short* __restrict__ f_tail)
{
    __shared__ unsigned short As[2][64 * 32];    // 4 KB per buf
    __shared__ unsigned short Bs[2][128 * 32];   // 8 KB per buf

    const int tid  = threadIdx.x;
    const int wave = tid >> 6;
    const int lane = tid & 63;
    const int n0 = blockIdx.x * 128;
    const int m0 = blockIdx.y * 64;

    const int srow = wave * 16 + (lane >> 2);          // 0..63
    const int scol = (lane & 3) * 8;                   // elements
    const unsigned short* Aga = Ab + (size_t)(m0 + srow) * GK + scol;
    const unsigned short* Bga = Wb + (size_t)(n0 + srow) * GK + scol;

#define STAGE(buf, k0) do { \
    __builtin_amdgcn_global_load_lds((const __attribute__((address_space(1))) void*)(Aga + (k0)), \
        (__attribute__((address_space(3))) void*)(As[buf] + wave * 512), 16, 0, 0); \
    __builtin_amdgcn_global_load_lds((const __attribute__((address_space(1))) void*)(Bga + (k0)), \
        (__attribute__((address_space(3))) void*)(Bs[buf] + wave * 512), 16, 0, 0); \
    __builtin_amdgcn_global_load_lds((const __attribute__((address_space(1))) void*)(Bga + 64 * GK + (k0)), \
        (__attribute__((address_space(3))) void*)(Bs[buf] + 2048 + wave * 512), 16, 0, 0); \
} while (0)

    const int frow = lane & 15;
    const int koff = (lane >> 4) * 8;

    f32x4 acc[4][2];
    {
        f32x4 z = {0.f, 0.f, 0.f, 0.f};
        #pragma unroll
        for (int mi = 0; mi < 4; ++mi) { acc[mi][0] = z; acc[mi][1] = z; }
    }

    STAGE(0, 0);
    int cur = 0;
    #pragma unroll 1
    for (int t = 0; t < NT; ++t) {
        __syncthreads();                 // drains vmcnt: buf[cur] ready
        if (t < NT - 1) STAGE(cur ^ 1, (t + 1) * 32);
        const unsigned short* ap = As[cur] + frow * 32 + koff;
        const unsigned short* bp = Bs[cur] + (wave * 32 + frow) * 32 + koff;
        bf16x8 a[4], b[2];
        #pragma unroll
        for (int mi = 0; mi < 4; ++mi)
            a[mi] = *reinterpret_cast<const bf16x8*>(ap + mi * 16 * 32);
        b[0] = *reinterpret_cast<const bf16x8*>(bp);
        b[1] = *reinterpret_cast<const bf16x8*>(bp + 16 * 32);
        #pragma unroll
        for (int mi = 0; mi < 4; ++mi) {
            acc[mi][0] = __builtin_amdgcn_mfma_f32_16x16x32_bf16(a[mi], b[0], acc[mi][0], 0, 0, 0);
            acc[mi][1] = __builtin_amdgcn_mfma_f32_16x16x32_bf16(a[mi], b[1], acc[mi][1], 0, 0, 0);
        }
        cur ^= 1;
    }
#undef STAGE

    // C/D layout (m89-verified): col = lane&15, row = (lane>>4)*4 + reg.
    const bool isHead = (n0 < Hd);
    unsigned short* outp = isHead ? f_head : f_tail;
    const int nbase = (isHead ? n0 : (n0 - Hd)) + wave * 32 + frow;
    const int rbase = m0 + (lane >> 4) * 4;
    #pragma unroll
    for (int mi = 0; mi < 4; ++mi)
        #pragma unroll
        for (int ni = 0; ni < 2; ++ni)
            #pragma unroll
            for (int j = 0; j < 4; ++j) {
                float v = fmaxf(acc[mi][ni][j], 0.f);
                outp[(size_t)(rbase + mi * 16 + j) * Hd + nbase + ni * 16] = f2bf(v);
            }
}

// ---------------------------------------------------------------------------
// Kernel 2: per-row dots (identical to round 5).
// ---------------------------------------------------------------------------
__global__ __launch_bounds__(256)
void row_dots(const unsigned short* __restrict__ f_head,
              const unsigned short* __restrict__ f_tail,
              const float* __restrict__ w_c, const float* __restrict__ w_q,
              const float* __restrict__ w_cq,
              float* __restrict__ ch, float* __restrict__ qt, float* __restrict__ cqt)
{
    const int wave = threadIdx.x >> 6;
    const int lane = threadIdx.x & 63;
    const int r = blockIdx.x * 4 + wave;
    const unsigned short* fh = f_head + (size_t)r * Hd;
    const unsigned short* ft = f_tail + (size_t)r * Hd;
    float pc = 0.f, pq = 0.f, pcq = 0.f;
    #pragma unroll
    for (int j = 0; j < Hd / 64; ++j) {
        const int c = j * 64 + lane;
        float vh = bf2f(fh[c]), vt = bf2f(ft[c]);
        pc += vh * w_c[c]; pq += vt * w_q[c]; pcq += vt * w_cq[c];
    }
    #pragma unroll
    for (int s = 32; s >= 1; s >>= 1) {
        pc  += __shfl_down(pc, s);
        pq  += __shfl_down(pq, s);
        pcq += __shfl_down(pcq, s);
    }
    if (lane == 0) { ch[r] = pc; qt[r] = pq; cqt[r] = pcq; }
}

// ---------------------------------------------------------------------------
// Kernel 3: ONE WAVE PER PAIR (4 pairs/block, 1024 blocks -> ~32 pairs/CU
// in flight vs 8 before).  Lane l owns score row i=l>>2, cols jg*4..jg*4+3.
// Row/col max + both softmaxes fully in-register via shfl_xor trees.
// Weights staged through 512B LDS for the pooling sweep.
// Pooling bounded at hn/tn (rows >= cnt have weight exactly 0: bit-exact).
// ---------------------------------------------------------------------------
__global__ __launch_bounds__(256)
void pair_attn(const unsigned short* __restrict__ f_head,
               const unsigned short* __restrict__ f_tail,
               const float* __restrict__ ch, const float* __restrict__ qt,
               const float* __restrict__ cqt,
               const float* __restrict__ entity_embed,
               const int* __restrict__ mention_num,
               const int* __restrict__ b_ind, const int* __restrict__ h_ind,
               const int* __restrict__ t_ind,
               float* __restrict__ out, int N)
{
    const int tid  = threadIdx.x;
    const int wave = tid >> 6;
    const int lane = tid & 63;

    __shared__ float hwS[4][16];
    __shared__ float twS[4][16];

    int n = blockIdx.x * 4 + wave;
    if (n >= N) n = N - 1;      // duplicate pair: identical writes, deterministic

    const int b = b_ind[n], h = h_ind[n], t = t_ind[n];
    const int eh = b * Ent + h, et = b * Ent + t;
    const int rh = eh * Mm, rt = et * Mm;
    const int hn = mention_num[eh], tn = mention_num[et];

    const int i  = lane >> 2;       // score row 0..15
    const int jg = lane & 3;        // col group: cols jg*4 .. jg*4+3

    // ---- scores (4 per lane) ----
    const float chi = ch[rh + i];
    const float cqi = cqt[rt + i];
    const float4 q4 = *reinterpret_cast<const float4*>(qt + rt + jg * 4);
    const u16x4 f4  = *reinterpret_cast<const u16x4*>(
                          f_head + (size_t)(rh + i) * Hd + jg * 4);
    float v[4];
    #pragma unroll
    for (int k = 0; k < 4; ++k) {
        const int j = jg * 4 + k;
        const float qv = (k == 0) ? q4.x : (k == 1) ? q4.y : (k == 2) ? q4.z : q4.w;
        v[k] = (i < hn && j < tn) ? (chi + qv + cqi * bf2f(f4[k])) : NEGV;
    }

    // ---- row max over j (lanes sharing i: xor 1,2) ----
    float rm = fmaxf(fmaxf(v[0], v[1]), fmaxf(v[2], v[3]));
    rm = fmaxf(rm, __shfl_xor(rm, 1));
    rm = fmaxf(rm, __shfl_xor(rm, 2));

    // ---- col max over i (lanes stride 4: xor 4,8,16,32) ----
    float cm[4];
    #pragma unroll
    for (int k = 0; k < 4; ++k) {
        cm[k] = v[k];
        cm[k] = fmaxf(cm[k], __shfl_xor(cm[k], 4));
        cm[k] = fmaxf(cm[k], __shfl_xor(cm[k], 8));
        cm[k] = fmaxf(cm[k], __shfl_xor(cm[k], 16));
        cm[k] = fmaxf(cm[k], __shfl_xor(cm[k], 32));
    }

    // ---- h softmax over rowmax (16 distinct i, uniform within i-group) ----
    float gm = rm;
    gm = fmaxf(gm, __shfl_xor(gm, 4));
    gm = fmaxf(gm, __shfl_xor(gm, 8));
    gm = fmaxf(gm, __shfl_xor(gm, 16));
    gm = fmaxf(gm, __shfl_xor(gm, 32));
    const float eh_ = expf(rm - gm);               // masked rows -> exactly 0
    float S = eh_;
    S += __shfl_xor(S, 4);
    S += __shfl_xor(S, 8);
    S += __shfl_xor(S, 16);
    S += __shfl_xor(S, 32);
    const float hwv = eh_ / S;                     // weight of row i

    // ---- t softmax over colmax (cm[k] duplicated across i-groups) ----
    float gmt = fmaxf(fmaxf(cm[0], cm[1]), fmaxf(cm[2], cm[3]));
    gmt = fmaxf(gmt, __shfl_xor(gmt, 1));
    gmt = fmaxf(gmt, __shfl_xor(gmt, 2));
    float et_[4];
    float St = 0.f;
    #pragma unroll
    for (int k = 0; k < 4; ++k) { et_[k] = expf(cm[k] - gmt); St += et_[k]; }
    St += __shfl_xor(St, 1);
    St += __shfl_xor(St, 2);

    if (jg == 0) hwS[wave][i] = hwv;
    if (lane < 4) {
        #pragma unroll
        for (int k = 0; k < 4; ++k) twS[wave][lane * 4 + k] = et_[k] / St;
    }
    __syncthreads();   // uniform across all 4 waves (every wave has a pair)

    // ---- pooling (3 chunks of 256 cols; lane owns 4 consecutive cols) ----
    const size_t oh = (size_t)n * (2 * Hd);
    const size_t ot = (size_t)(N + n) * (2 * Hd);
    const unsigned short* fhp = f_head + (size_t)rh * Hd;
    const unsigned short* ftp = f_tail + (size_t)rt * Hd;

    #pragma unroll
    for (int c = 0; c < 3; ++c) {
        const int col = c * 256 + lane * 4;
        float a0 = 0.f, a1 = 0.f, a2 = 0.f, a3 = 0.f;
        for (int ii = 0; ii < hn; ++ii) {
            const u16x4 fv = *reinterpret_cast<const u16x4*>(fhp + (size_t)ii * Hd + col);
            const float w = hwS[wave][ii];
            a0 += w * bf2f(fv[0]); a1 += w * bf2f(fv[1]);
            a2 += w * bf2f(fv[2]); a3 += w * bf2f(fv[3]);
        }
        float4 o = {a0, a1, a2, a3};
        *reinterpret_cast<float4*>(out + oh + Hd + col) = o;
    }
    #pragma unroll
    for (int c = 0; c < 3; ++c) {
        const int col = c * 256 + lane * 4;
        float a0 = 0.f, a1 = 0.f, a2 = 0.f, a3 = 0.f;
        for (int ii = 0; ii < tn; ++ii) {
            const u16x4 fv = *reinterpret_cast<const u16x4*>(ftp + (size_t)ii * Hd + col);
            const float w = twS[wave][ii];
            a0 += w * bf2f(fv[0]); a1 += w * bf2f(fv[1]);
            a2 += w * bf2f(fv[2]); a3 += w * bf2f(fv[3]);
        }
        float4 o = {a0, a1, a2, a3};
        *reinterpret_cast<float4*>(out + ot + Hd + col) = o;
    }

    // ---- entity embed copy: 2 x 192 float4, lane covers 3 each ----
    const float4* ehp = reinterpret_cast<const float4*>(entity_embed + (size_t)eh * Hd);
    const float4* etp = reinterpret_cast<const float4*>(entity_embed + (size_t)et * Hd);
    #pragma unroll
    for (int c = 0; c < 3; ++c) {
        const int g = c * 64 + lane;
        reinterpret_cast<float4*>(out + oh)[g] = ehp[g];
        reinterpret_cast<float4*>(out + ot)[g] = etp[g];
    }
}

// ---------------------------------------------------------------------------
extern "C" void kernel_launch(void* const* d_in, const int* in_sizes, int n_in,
                              void* d_out, int out_size, void* d_ws, size_t ws_size,
                              hipStream_t stream)
{
    const float* entity_embed  = (const float*)d_in[0];
    const float* mention_embed = (const float*)d_in[1];
    // d_in[2] sent_embed, d_in[3] entity_info: unused by reference
    const int*   mention_num   = (const int*)d_in[4];
    const int*   b_ind         = (const int*)d_in[5];
    const int*   h_ind         = (const int*)d_in[6];
    const int*   t_ind         = (const int*)d_in[7];
    const float* W_head        = (const float*)d_in[8];
    const float* W_tail        = (const float*)d_in[9];
    const float* w_c           = (const float*)d_in[10];
    const float* w_q           = (const float*)d_in[11];
    const float* w_cq          = (const float*)d_in[12];
    float* out = (float*)d_out;

    const int N = in_sizes[5];            // 4096

    // workspace layout (bf16 activations): total ~14.8 MiB
    unsigned short* Ab     = (unsigned short*)d_ws;          // [2688*768]
    unsigned short* Wb     = Ab + (size_t)GM * GK;           // [1536*768] (head||tail)
    unsigned short* f_head = Wb + (size_t)GN * GK;           // [2688*768]
    unsigned short* f_tail = f_head + (size_t)GM * Hd;       // [2688*768]
    float* ch  = (float*)(f_tail + (size_t)GM * Hd);
    float* qt  = ch + GM;
    float* cqt = qt + GM;

    // 0) convert inputs to bf16
    to_bf16<<<(GM + GN) * GK / (8 * 256), 256, 0, stream>>>(
        mention_embed, W_head, W_tail, Ab);

    // 1) fused projection GEMM + ReLU -> bf16 f_head / f_tail
    dim3 gg(GN / 128, GM / 64);           // (12, 42) = 504 blocks
    gemm_mfma<<<gg, 256, 0, stream>>>(Ab, Wb, f_head, f_tail);

    // 2) per-row dots
    row_dots<<<GM / 4, 256, 0, stream>>>(f_head, f_tail, w_c, w_q, w_cq, ch, qt, cqt);

    // 3) per-pair attention + output (wave per pair)
    pair_attn<<<(N + 3) / 4, 256, 0, stream>>>(f_head, f_tail, ch, qt, cqt,
                                               entity_embed, mention_num,
                                               b_ind, h_ind, t_ind, out, N);
}